// Round 1
// baseline (211.339 us; speedup 1.0000x reference)
//
#include <hip/hip_runtime.h>

// Reference reduces to: out[w,h] = -( (Σ_{k=0..8} fl(1e-14f*W[k]) * patch[k]) / C2 ) * 1500
// with C2 = (float)(0.924458 * 1e-14 * 1500.0)  [double math, rounded once to fp32],
// patch[k] = x[3w + k/3, 3h + k%3], sequential left-fold accumulation, no FMA.
// Pure HBM-bound streaming op: 151 MB read + 16.8 MB write ≈ 27 us floor.

#define IN_H 6144   // input rows
#define IN_W 6144   // input cols (row-major)
#define OUT_H 2048
#define OUT_W 2048
#define QW 512      // OUT_W / 4 : each thread makes 4 adjacent outputs

__global__ __launch_bounds__(256) void conv3x3_sc_kernel(
    const float* __restrict__ x,
    const float* __restrict__ w,
    float* __restrict__ out)
{
    const int t = blockIdx.x * blockDim.x + threadIdx.x;
    if (t >= OUT_H * QW) return;

    const int ow = t / QW;        // output row
    const int hq = t - ow * QW;   // output quad-column (4 outputs)

    // caps: cw[k] = fl(1e-14f * w[k])  (matches caps = C_BASE * (bits @ [1,2,4,8]))
    float cw[9];
#pragma unroll
    for (int i = 0; i < 9; ++i) cw[i] = __fmul_rn(1e-14f, w[i]);

    const float* r0 = x + (size_t)(3 * ow) * IN_W + 12 * hq;  // 48B-aligned
    const float* r1 = r0 + IN_W;
    const float* r2 = r1 + IN_W;

    const float4 a0 = *(const float4*)(r0);
    const float4 a1 = *(const float4*)(r0 + 4);
    const float4 a2 = *(const float4*)(r0 + 8);
    const float4 b0 = *(const float4*)(r1);
    const float4 b1 = *(const float4*)(r1 + 4);
    const float4 b2 = *(const float4*)(r1 + 8);
    const float4 c0 = *(const float4*)(r2);
    const float4 c1 = *(const float4*)(r2 + 4);
    const float4 c2 = *(const float4*)(r2 + 8);

    const float ra[12] = {a0.x,a0.y,a0.z,a0.w, a1.x,a1.y,a1.z,a1.w, a2.x,a2.y,a2.z,a2.w};
    const float rb[12] = {b0.x,b0.y,b0.z,b0.w, b1.x,b1.y,b1.z,b1.w, b2.x,b2.y,b2.z,b2.w};
    const float rc[12] = {c0.x,c0.y,c0.z,c0.w, c1.x,c1.y,c1.z,c1.w, c2.x,c2.y,c2.z,c2.w};

    // C2 computed in double (as Python does), rounded once to fp32 at use.
    const float C2 = (float)(0.924458 * 1e-14 * 1500.0);

    float o[4];
#pragma unroll
    for (int k = 0; k < 4; ++k) {
        const int cb = 3 * k;
        // sequential left-fold, k = 0..8, mul-then-add, round-to-nearest (no contraction)
        float acc =            __fmul_rn(cw[0], ra[cb + 0]);
        acc = __fadd_rn(acc,   __fmul_rn(cw[1], ra[cb + 1]));
        acc = __fadd_rn(acc,   __fmul_rn(cw[2], ra[cb + 2]));
        acc = __fadd_rn(acc,   __fmul_rn(cw[3], rb[cb + 0]));
        acc = __fadd_rn(acc,   __fmul_rn(cw[4], rb[cb + 1]));
        acc = __fadd_rn(acc,   __fmul_rn(cw[5], rb[cb + 2]));
        acc = __fadd_rn(acc,   __fmul_rn(cw[6], rc[cb + 0]));
        acc = __fadd_rn(acc,   __fmul_rn(cw[7], rc[cb + 1]));
        acc = __fadd_rn(acc,   __fmul_rn(cw[8], rc[cb + 2]));
        // voltage = q2 / c2 * 1500 ; out = -voltage
        o[k] = -__fmul_rn(__fdiv_rn(acc, C2), 1500.0f);
    }

    float4 ov = make_float4(o[0], o[1], o[2], o[3]);
    *(float4*)(out + (size_t)ow * OUT_W + 4 * hq) = ov;
}

extern "C" void kernel_launch(void* const* d_in, const int* in_sizes, int n_in,
                              void* d_out, int out_size, void* d_ws, size_t ws_size,
                              hipStream_t stream) {
    (void)in_sizes; (void)n_in; (void)out_size; (void)d_ws; (void)ws_size;
    const float* x = (const float*)d_in[0];
    const float* w = (const float*)d_in[1];
    float* out = (float*)d_out;

    const int total = OUT_H * QW;            // 1,048,576 threads
    const int block = 256;
    const int grid = (total + block - 1) / block;  // 4096 blocks
    conv3x3_sc_kernel<<<grid, block, 0, stream>>>(x, w, out);
}